// Round 10
// baseline (522.604 us; speedup 1.0000x reference)
//
#include <hip/hip_runtime.h>
#include <hip/hip_bf16.h>
#include <math.h>

#define NN 50000
#define NE 800000
#define NB 512
#define FIN 74
#define HD 64
#define BN_EPS 1e-5f

#define SCHUNK 512
#define NCHUNK ((NN + SCHUNK - 1) / SCHUNK)  // 98

#define CHUNK 32
#define ELLW 32
#define NBLK ((NN + CHUNK - 1) / CHUNK)  // 1563

#define BROWS 64
#define NBUCK ((NN + BROWS - 1) / BROWS)  // 782

// ---------------- CSR build ----------------

// zero counters + stats + zero-row; pack layer-0 weights into (W,rW) float2 pairs
__global__ void csr_zero_kernel(int* __restrict__ cnt, int* __restrict__ bcnt,
                                float* __restrict__ stats012,
                                unsigned long long* __restrict__ xw_zrow,
                                const float* __restrict__ W0, const float* __restrict__ rW0,
                                float2* __restrict__ Wpk0) {
    int i = blockIdx.x * 256 + threadIdx.x;
    if (i < NN) cnt[i] = 0;
    if (i < NBUCK) bcnt[i] = 0;
    if (i < 384) stats012[i] = 0.f;
    if (i < 16) xw_zrow[i] = 0ull;  // XW row NN = 128 B of zeros
    if (i < FIN * HD) Wpk0[i] = make_float2(W0[i], rW0[i]);
}

__global__ void csr_hist_kernel(const int* __restrict__ dst, int* __restrict__ cnt) {
    int e = blockIdx.x * 256 + threadIdx.x;
    if (e < NE) atomicAdd(&cnt[dst[e]], 1);
}

__global__ void scanA_kernel(const int* __restrict__ cnt, int* __restrict__ bsum) {
    __shared__ int l[SCHUNK];
    int i = blockIdx.x * SCHUNK + threadIdx.x;
    int v = (i < NN) ? cnt[i] : 0;
    l[threadIdx.x] = v;
    __syncthreads();
    for (int off = SCHUNK / 2; off; off >>= 1) {
        if (threadIdx.x < off) l[threadIdx.x] += l[threadIdx.x + off];
        __syncthreads();
    }
    if (threadIdx.x == 0) bsum[blockIdx.x] = l[0];
}

__global__ void scanB_kernel(int* __restrict__ bsum) {
    int lane = threadIdx.x;  // 64 threads
    int v0 = (lane < NCHUNK) ? bsum[lane] : 0;
    int v1 = (64 + lane < NCHUNK) ? bsum[64 + lane] : 0;
    int s0 = v0, s1 = v1;
    for (int off = 1; off < 64; off <<= 1) {
        int t0 = __shfl_up(s0, off, 64);
        int t1 = __shfl_up(s1, off, 64);
        if (lane >= off) { s0 += t0; s1 += t1; }
    }
    int tot0 = __shfl(s0, 63, 64);
    if (lane < NCHUNK) bsum[lane] = s0 - v0;
    if (64 + lane < NCHUNK) bsum[64 + lane] = s1 - v1 + tot0;
}

__global__ void scanC_kernel(const int* __restrict__ cnt, const int* __restrict__ bsum,
                             int* __restrict__ row_ptr) {
    __shared__ int l[SCHUNK];
    int i = blockIdx.x * SCHUNK + threadIdx.x;
    int v = (i < NN) ? cnt[i] : 0;
    l[threadIdx.x] = v;
    __syncthreads();
    for (int off = 1; off < SCHUNK; off <<= 1) {
        int t = (threadIdx.x >= off) ? l[threadIdx.x - off] : 0;
        __syncthreads();
        l[threadIdx.x] += t;
        __syncthreads();
    }
    int excl = l[threadIdx.x] - v + bsum[blockIdx.x];
    if (i < NN) row_ptr[i] = excl;
    if (i == NN - 1) row_ptr[NN] = excl + v;
}

// pass 1: scatter (src,dst) pairs into bucket-contiguous staging.
// bucket base = row_ptr[64*bk] (exact capacity); slots sequential within bucket
// -> stores fill whole cache lines instead of dirtying one dword per line.
__global__ void bucket_scatter_kernel(const int* __restrict__ src, const int* __restrict__ dst,
                                      const int* __restrict__ row_ptr, int* __restrict__ bcnt,
                                      int2* __restrict__ pairs) {
    int e = blockIdx.x * 256 + threadIdx.x;
    if (e < NE) {
        int d = dst[e];
        int bk = d >> 6;
        int base = row_ptr[bk << 6];  // 782 hot entries, L1-resident
        int p = base + atomicAdd(&bcnt[bk], 1);
        pairs[p] = make_int2(src[e], d);
    }
}

// pass 2: one block per bucket; rank-within-row via LDS atomics; dense eidx writes.
__global__ void bucket_fill_kernel(const int2* __restrict__ pairs,
                                   const int* __restrict__ row_ptr, int* __restrict__ eidx) {
    __shared__ int lcnt[BROWS];
    __shared__ int sRPb[BROWS + 1];
    int bk = blockIdx.x;
    int rbase = bk * BROWS;
    int tid = threadIdx.x;
    if (tid <= BROWS) {
        int rp = rbase + tid;
        sRPb[tid] = row_ptr[(rp < NN) ? rp : NN];
    }
    if (tid < BROWS) lcnt[tid] = 0;
    __syncthreads();
    int beg = sRPb[0], end = sRPb[BROWS];
    for (int i = beg + tid; i < end; i += 256) {
        int2 pr = pairs[i];
        int r = pr.y - rbase;
        int ls = atomicAdd(&lcnt[r], 1);
        eidx[sRPb[r] + ls] = pr.x;
    }
}

// ---------------- dense pieces ----------------

// Row-blocked dual GEMM: xw = x @ W1 (bf16); res = relu(x @ W2 + rb) (bf16).
template <int K>
__global__ __launch_bounds__(256) void gemm_dual_kernel(
    const float* __restrict__ x, const float2* __restrict__ Wpk,
    const float* __restrict__ rb, __hip_bfloat16* __restrict__ xw,
    __hip_bfloat16* __restrict__ res, int n) {
    __shared__ float2 sW[K * HD];
    __shared__ float srb[64];
    for (int i = threadIdx.x; i < K * HD; i += 256) sW[i] = Wpk[i];
    if (threadIdx.x < 64) srb[threadIdx.x] = rb[threadIdx.x];
    __syncthreads();
    int wl = threadIdx.x >> 6, lane = threadIdx.x & 63;
    for (int r0 = (blockIdx.x * 4 + wl) * 8; r0 < n; r0 += gridDim.x * 32) {
        float a1[8], a2[8];
#pragma unroll
        for (int r = 0; r < 8; ++r) { a1[r] = 0.f; a2[r] = 0.f; }
#pragma unroll
        for (int c0 = 0; c0 < K; c0 += 64) {
            const int cl = (K - c0 < 64) ? (K - c0) : 64;
            float xv[8];
#pragma unroll
            for (int r = 0; r < 8; ++r) {
                int row = r0 + r;
                xv[r] = (lane < cl && row < n) ? x[(size_t)row * K + c0 + lane] : 0.f;
            }
            for (int j = 0; j < cl; ++j) {
                float2 w = sW[(c0 + j) * HD + lane];
#pragma unroll
                for (int r = 0; r < 8; ++r) {
                    float xb = __uint_as_float(
                        __builtin_amdgcn_readlane(__float_as_uint(xv[r]), j));
                    a1[r] = fmaf(xb, w.x, a1[r]);
                    a2[r] = fmaf(xb, w.y, a2[r]);
                }
            }
        }
#pragma unroll
        for (int r = 0; r < 8; ++r) {
            int row = r0 + r;
            if (row < n) {
                xw[(size_t)row * HD + lane] = __float2bfloat16(a1[r]);
                res[(size_t)row * HD + lane] = __float2bfloat16(fmaxf(a2[r] + srb[lane], 0.f));
            }
        }
    }
}

// BN fold for layer l>=1: writes packed (Wp,rWp) float2 + shiftW + rbp
__global__ void fold_kernel(const float* __restrict__ stats, const float* __restrict__ g,
                            const float* __restrict__ be, const float* __restrict__ W,
                            const float* __restrict__ rW, const float* __restrict__ rb,
                            float2* __restrict__ Wpk, float* __restrict__ shiftW,
                            float* __restrict__ rbp) {
    __shared__ float sc[64], sh[64];
    int t = threadIdx.x;
    if (t < 64) {
        float mean = stats[t] / (float)NN;
        float var = stats[64 + t] / (float)NN - mean * mean;
        float scale = g[t] * rsqrtf(var + BN_EPS);
        sc[t] = scale;
        sh[t] = be[t] - mean * scale;
    }
    __syncthreads();
    for (int i = t; i < 64 * 64; i += 256) {
        int k = i >> 6;
        Wpk[i] = make_float2(sc[k] * W[i], sc[k] * rW[i]);
    }
    if (t < 64) {
        float sw = 0.f, srw = 0.f;
        for (int k = 0; k < 64; ++k) {
            sw = fmaf(sh[k], W[k * 64 + t], sw);
            srw = fmaf(sh[k], rW[k * 64 + t], srw);
        }
        shiftW[t] = sw;
        rbp[t] = rb[t] + srw;
    }
}

__device__ __forceinline__ float bf_lo(unsigned int p) { return __uint_as_float(p << 16); }
__device__ __forceinline__ float bf_hi(unsigned int p) { return __uint_as_float(p & 0xffff0000u); }

// 16-slot branch-free gather batch (pads hit the hot zero row -> L1)
#define GATHER16(BASE)                                             \
    {                                                              \
        unsigned long long d[16];                                  \
        _Pragma("unroll") for (int j = 0; j < 16; ++j) {           \
            int idx = sIdx[rloc][(BASE) + j];                      \
            unsigned off = (unsigned)idx * 16u + (unsigned)c8;     \
            d[j] = XWu[off];                                       \
        }                                                          \
        _Pragma("unroll") for (int j = 0; j < 16; ++j) {           \
            unsigned lo = (unsigned)d[j], hi = (unsigned)(d[j] >> 32); \
            a0 += bf_lo(lo); a1 += bf_hi(lo);                      \
            a2 += bf_lo(hi); a3 += bf_hi(hi);                      \
        }                                                          \
    }

// fused aggregation v4: 16 lanes/row (8-B loads), 4 rows in flight per wave step,
// fixed-16 branch-free phases. h = relu(gather + deg*shiftW + b) + res; stats += (h,h^2).
__global__ __launch_bounds__(256, 4) void fused_agg_kernel(
    const __hip_bfloat16* __restrict__ xw, const __hip_bfloat16* __restrict__ res,
    const float* __restrict__ b, const float* __restrict__ shiftW,
    const int* __restrict__ row_ptr, const int* __restrict__ geidx,
    float* __restrict__ hout, float* __restrict__ stats, int n) {
    __shared__ int sIdx[CHUNK][ELLW + 1];  // +1 pad: spread quarter broadcasts over banks
    __shared__ int sRP[CHUNK + 1];
    __shared__ int sLen[CHUNK];
    __shared__ float sbb[128];          // b | shiftW
    __shared__ float lsr[4][16][8];     // wave x c8 x {4 sums, 4 sumsqs}

    int tid = threadIdx.x;
    int r0 = blockIdx.x * CHUNK;

    if (tid <= CHUNK) {
        int rp = r0 + tid;
        sRP[tid] = row_ptr[(rp < NN) ? rp : NN];
    }
    if (tid >= 128 && tid < 256) {
        int j = tid - 128;
        sbb[j] = (j < 64) ? b[j] : (shiftW ? shiftW[j - 64] : 0.f);
    }
    __syncthreads();
    for (int i = tid; i < CHUNK * ELLW; i += 256) {
        int r = i >> 5, j = i & 31;
        int beg = sRP[r];
        int plen = sRP[r + 1] - beg;
        sIdx[r][j] = (j < plen) ? geidx[beg + j] : NN;
        if (j == 0) sLen[r] = plen;
    }
    __syncthreads();

    const unsigned long long* XWu = (const unsigned long long*)xw;
    const unsigned long long* REu = (const unsigned long long*)res;
    int wl = tid >> 6, lane = tid & 63;
    int q = lane >> 4, c8 = lane & 15;
    float sb0 = sbb[4 * c8], sb1 = sbb[4 * c8 + 1], sb2 = sbb[4 * c8 + 2], sb3 = sbb[4 * c8 + 3];
    float sw0 = sbb[64 + 4 * c8], sw1 = sbb[64 + 4 * c8 + 1];
    float sw2 = sbb[64 + 4 * c8 + 2], sw3 = sbb[64 + 4 * c8 + 3];
    float s0 = 0.f, s1 = 0.f, s2 = 0.f, s3 = 0.f;
    float q0 = 0.f, q1 = 0.f, q2 = 0.f, q3 = 0.f;

#pragma unroll
    for (int p = 0; p < 2; ++p) {
        int rbase = wl * 8 + p * 4;
        int rloc = rbase + q;
        int grow = r0 + rloc;
        int growc = (grow < n) ? grow : (n - 1);
        int l0 = sLen[rbase], l1 = sLen[rbase + 1], l2 = sLen[rbase + 2], l3 = sLen[rbase + 3];
        int m01 = (l0 > l1) ? l0 : l1, m23 = (l2 > l3) ? l2 : l3;
        int kmax = (m01 > m23) ? m01 : m23;  // wave-uniform
        int mylen = sLen[rloc];
        unsigned long long rqw = REu[(unsigned)growc * 16u + (unsigned)c8];  // residual early
        float a0 = 0.f, a1 = 0.f, a2 = 0.f, a3 = 0.f;
        GATHER16(0)
        if (kmax > 16) GATHER16(16)
        if (kmax > ELLW) {  // rare (deg > 32), uniform
            int beg = sRP[rloc];
            for (int k = ELLW; k < kmax; ++k) {
                int idx = geidx[beg + k];  // in-bounds; value-select below
                unsigned off = (unsigned)((k < mylen) ? idx : NN) * 16u + (unsigned)c8;
                unsigned long long u = XWu[off];
                unsigned lo = (unsigned)u, hi = (unsigned)(u >> 32);
                a0 += bf_lo(lo); a1 += bf_hi(lo);
                a2 += bf_lo(hi); a3 += bf_hi(hi);
            }
        }
        unsigned rlo = (unsigned)rqw, rhi = (unsigned)(rqw >> 32);
        float dg = (float)mylen;
        float h0 = fmaxf(a0 + fmaf(dg, sw0, sb0), 0.f) + bf_lo(rlo);
        float h1 = fmaxf(a1 + fmaf(dg, sw1, sb1), 0.f) + bf_hi(rlo);
        float h2 = fmaxf(a2 + fmaf(dg, sw2, sb2), 0.f) + bf_lo(rhi);
        float h3 = fmaxf(a3 + fmaf(dg, sw3, sb3), 0.f) + bf_hi(rhi);
        if (grow < n) {
            *(float4*)&hout[(unsigned)grow * 64u + 4u * c8] = make_float4(h0, h1, h2, h3);
            s0 += h0; s1 += h1; s2 += h2; s3 += h3;
            q0 += h0 * h0; q1 += h1 * h1; q2 += h2 * h2; q3 += h3 * h3;
        }
    }

    // reduce across the 4 quarters of the wave (same c8 -> same columns)
    s0 += __shfl_xor(s0, 16, 64); s0 += __shfl_xor(s0, 32, 64);
    s1 += __shfl_xor(s1, 16, 64); s1 += __shfl_xor(s1, 32, 64);
    s2 += __shfl_xor(s2, 16, 64); s2 += __shfl_xor(s2, 32, 64);
    s3 += __shfl_xor(s3, 16, 64); s3 += __shfl_xor(s3, 32, 64);
    q0 += __shfl_xor(q0, 16, 64); q0 += __shfl_xor(q0, 32, 64);
    q1 += __shfl_xor(q1, 16, 64); q1 += __shfl_xor(q1, 32, 64);
    q2 += __shfl_xor(q2, 16, 64); q2 += __shfl_xor(q2, 32, 64);
    q3 += __shfl_xor(q3, 16, 64); q3 += __shfl_xor(q3, 32, 64);
    if (q == 0) {
        lsr[wl][c8][0] = s0; lsr[wl][c8][1] = s1; lsr[wl][c8][2] = s2; lsr[wl][c8][3] = s3;
        lsr[wl][c8][4] = q0; lsr[wl][c8][5] = q1; lsr[wl][c8][6] = q2; lsr[wl][c8][7] = q3;
    }
    __syncthreads();
    if (tid < 64) {
        int c8i = tid >> 2, comp = tid & 3;
        float ssum = lsr[0][c8i][comp] + lsr[1][c8i][comp] + lsr[2][c8i][comp] + lsr[3][c8i][comp];
        float qsum = lsr[0][c8i][4 + comp] + lsr[1][c8i][4 + comp] + lsr[2][c8i][4 + comp] +
                     lsr[3][c8i][4 + comp];
        atomicAdd(&stats[tid], ssum);
        atomicAdd(&stats[64 + tid], qsum);
    }
}

// ---------------- readout ----------------

__global__ void readout_init_kernel(float* __restrict__ hsum, unsigned int* __restrict__ hmax,
                                    const float* __restrict__ stats, const float* __restrict__ g,
                                    const float* __restrict__ be, float* __restrict__ ss) {
    int idx = blockIdx.x * 256 + threadIdx.x;
    if (idx < NB * HD) {
        hsum[idx] = 0.f;
        hmax[idx] = 0x007FFFFFu;  // encoded(-inf)
    }
    if (blockIdx.x == 0 && threadIdx.x < 64) {
        int c = threadIdx.x;
        float mean = stats[c] / (float)NN;
        float var = stats[64 + c] / (float)NN - mean * mean;
        float scale = g[c] * rsqrtf(var + BN_EPS);
        ss[c] = scale;
        ss[64 + c] = be[c] - mean * scale;
    }
}

#define RNODES 16

__device__ __forceinline__ void ro_flush(float* hsum, unsigned int* hmax, int g, int c,
                                         float accS, float accM) {
    atomicAdd(&hsum[g * HD + c], accS);
    unsigned int bits = __float_as_uint(accM);
    unsigned int enc = (bits & 0x80000000u) ? ~bits : (bits | 0x80000000u);
    atomicMax(&hmax[g * HD + c], enc);
}

__global__ __launch_bounds__(256) void readout_kernel(
    const float* __restrict__ h, const int* __restrict__ gid, const float* __restrict__ ss,
    const float* __restrict__ awW, const float* __restrict__ awb, float* __restrict__ hsum,
    unsigned int* __restrict__ hmax, int n) {
    int wid = blockIdx.x * 4 + (threadIdx.x >> 6);
    int c = threadIdx.x & 63;
    int r0 = wid * RNODES;
    if (r0 >= n) return;
    int r1 = r0 + RNODES;
    if (r1 > n) r1 = n;
    float aw = awW[c], ab = awb[0];
    float sA = ss[c], sB = ss[64 + c];
    int cur = gid[r0];
    float accS = 0.f, accM = -__builtin_inff();
    for (int r = r0; r < r1; ++r) {
        int g = gid[r];
        if (g != cur) {
            ro_flush(hsum, hmax, cur, c, accS, accM);
            accS = 0.f;
            accM = -__builtin_inff();
            cur = g;
        }
        float v = fmaf(h[(size_t)r * HD + c], sA, sB);
        float p = v * aw;
        for (int off = 32; off; off >>= 1) p += __shfl_xor(p, off, 64);
        float w = 1.f / (1.f + expf(-(p + ab)));
        accS = fmaf(v, w, accS);
        accM = fmaxf(accM, v);
    }
    ro_flush(hsum, hmax, cur, c, accS, accM);
}

__global__ void final_kernel(const float* __restrict__ hsum, const unsigned int* __restrict__ hmax,
                             const float* __restrict__ outW, const float* __restrict__ outb,
                             float* __restrict__ out) {
    __shared__ float sW[128 * 64];
    for (int i = threadIdx.x; i < 128 * 64; i += 256) sW[i] = outW[i];
    __syncthreads();
    int idx = blockIdx.x * 256 + threadIdx.x;
    if (idx >= NB * HD) return;
    int bi = idx >> 6, o = idx & 63;
    float acc = outb[o];
#pragma unroll 4
    for (int k = 0; k < 64; ++k) acc = fmaf(hsum[bi * 64 + k], sW[k * 64 + o], acc);
#pragma unroll 4
    for (int k = 0; k < 64; ++k) {
        unsigned int e = hmax[bi * 64 + k];
        float m;
        if (e == 0x007FFFFFu) {
            m = 0.f;  // empty graph
        } else {
            m = (e & 0x80000000u) ? __uint_as_float(e ^ 0x80000000u) : __uint_as_float(~e);
        }
        acc = fmaf(m, sW[(64 + k) * 64 + o], acc);
    }
    out[idx] = acc;
}

// ---------------- launch ----------------

extern "C" void kernel_launch(void* const* d_in, const int* in_sizes, int n_in,
                              void* d_out, int out_size, void* d_ws, size_t ws_size,
                              hipStream_t stream) {
    const float* feats = (const float*)d_in[0];
    const int* src = (const int*)d_in[1];
    const int* dst = (const int*)d_in[2];
    const int* gid = (const int*)d_in[3];
    const float* W[3];
    const float* b[3];
    const float* rW[3];
    const float* rb[3];
    const float* g[3];
    const float* be[3];
    for (int l = 0; l < 3; ++l) {
        W[l] = (const float*)d_in[4 + 6 * l + 0];
        b[l] = (const float*)d_in[4 + 6 * l + 1];
        rW[l] = (const float*)d_in[4 + 6 * l + 2];
        rb[l] = (const float*)d_in[4 + 6 * l + 3];
        g[l] = (const float*)d_in[4 + 6 * l + 4];
        be[l] = (const float*)d_in[4 + 6 * l + 5];
    }
    const float* awW = (const float*)d_in[22];
    const float* awb = (const float*)d_in[23];
    const float* outW = (const float*)d_in[24];
    const float* outb = (const float*)d_in[25];
    float* out = (float*)d_out;

    // workspace layout (pairs placed on 8-B-aligned boundary before int arrays)
    __hip_bfloat16* XW = (__hip_bfloat16*)d_ws;                 // (NN+1)*64 bf16 (row NN zeros)
    __hip_bfloat16* RES = XW + (size_t)(NN + 1) * HD;           // NN*64 bf16
    float* P1 = (float*)(RES + (size_t)NN * HD);                // N*64 f32 (h, in place)
    float* stats = P1 + (size_t)NN * HD;                        // 3*128
    float* ss2 = stats + 384;                                   // 128
    float2* WPK = (float2*)(ss2 + 128);                         // FIN*HD float2
    float* shW = (float*)(WPK + FIN * HD);                      // 64
    float* rbp = shW + 64;                                      // 64
    float* hsum = rbp + 64;                                     // B*64
    unsigned int* hmax = (unsigned int*)(hsum + (size_t)NB * HD);  // B*64
    int2* pairs = (int2*)(hmax + (size_t)NB * HD);              // NE int2 (8-B aligned)
    int* cnt = (int*)(pairs + (size_t)NE);                      // N
    int* row_ptr = cnt + NN;                                    // N+1
    int* bsum = row_ptr + NN + 1;                               // NCHUNK
    int* bcnt = bsum + NCHUNK;                                  // NBUCK
    int* eidx = bcnt + NBUCK;                                   // NE

    float* stats0 = stats;
    float* stats1 = stats + 128;
    float* stats2 = stats + 256;

    const int EBLK = (NE + 255) / 256;
    const int GEMMBLK = 1280;
    const int ROBLK = (NN + RNODES * 4 - 1) / (RNODES * 4);

    // ---- CSR build (bucketed two-pass fill) + layer-0 weight pack ----
    csr_zero_kernel<<<(NN + 255) / 256, 256, 0, stream>>>(
        cnt, bcnt, stats, (unsigned long long*)(XW + (size_t)NN * HD), W[0], rW[0], WPK);
    csr_hist_kernel<<<EBLK, 256, 0, stream>>>(dst, cnt);
    scanA_kernel<<<NCHUNK, SCHUNK, 0, stream>>>(cnt, bsum);
    scanB_kernel<<<1, 64, 0, stream>>>(bsum);
    scanC_kernel<<<NCHUNK, SCHUNK, 0, stream>>>(cnt, bsum, row_ptr);
    bucket_scatter_kernel<<<EBLK, 256, 0, stream>>>(src, dst, row_ptr, bcnt, pairs);
    bucket_fill_kernel<<<NBUCK, 256, 0, stream>>>(pairs, row_ptr, eidx);

    // ---- layer 0 ----
    gemm_dual_kernel<FIN><<<GEMMBLK, 256, 0, stream>>>(feats, WPK, rb[0], XW, RES, NN);
    fused_agg_kernel<<<NBLK, 256, 0, stream>>>(XW, RES, b[0], (const float*)nullptr, row_ptr,
                                               eidx, P1, stats0, NN);

    // ---- layer 1 (fold BN0) ----
    fold_kernel<<<1, 256, 0, stream>>>(stats0, g[0], be[0], W[1], rW[1], rb[1], WPK, shW, rbp);
    gemm_dual_kernel<HD><<<GEMMBLK, 256, 0, stream>>>(P1, WPK, rbp, XW, RES, NN);
    fused_agg_kernel<<<NBLK, 256, 0, stream>>>(XW, RES, b[1], shW, row_ptr, eidx, P1, stats1, NN);

    // ---- layer 2 (fold BN1) ----
    fold_kernel<<<1, 256, 0, stream>>>(stats1, g[1], be[1], W[2], rW[2], rb[2], WPK, shW, rbp);
    gemm_dual_kernel<HD><<<GEMMBLK, 256, 0, stream>>>(P1, WPK, rbp, XW, RES, NN);
    fused_agg_kernel<<<NBLK, 256, 0, stream>>>(XW, RES, b[2], shW, row_ptr, eidx, P1, stats2, NN);

    // ---- readout (BN2 on the fly) ----
    readout_init_kernel<<<(NB * HD + 255) / 256, 256, 0, stream>>>(hsum, hmax, stats2, g[2], be[2], ss2);
    readout_kernel<<<ROBLK, 256, 0, stream>>>(P1, gid, ss2, awW, awb, hsum, hmax, NN);
    final_kernel<<<(NB * HD + 255) / 256, 256, 0, stream>>>(hsum, hmax, outW, outb, out);
}

// Round 11
// 322.958 us; speedup vs baseline: 1.6182x; 1.6182x over previous
//
#include <hip/hip_runtime.h>
#include <hip/hip_bf16.h>
#include <math.h>

#define NN 50000
#define NE 800000
#define NB 512
#define FIN 74
#define HD 64
#define BN_EPS 1e-5f

#define CHUNK 32
#define ELLW 32
#define NBLK ((NN + CHUNK - 1) / CHUNK)   // 1563
#define NBUCK2 NBLK                       // bucket == fused_agg block (32 rows)
#define EB2 128
#define EPB (NE / EB2)                    // 6250
#define OCAP 512

// ---------------- build (contention-free counting sort by 32-row bucket) ----------------

// zero stats + XW zero-row; pack layer-0 weights into (W,rW) float2 pairs
__global__ void init_kernel(float* __restrict__ stats012,
                            unsigned long long* __restrict__ xw_zrow,
                            const float* __restrict__ W0, const float* __restrict__ rW0,
                            float2* __restrict__ Wpk0) {
    int i = blockIdx.x * 256 + threadIdx.x;
    if (i < 384) stats012[i] = 0.f;
    if (i < 16) xw_zrow[i] = 0ull;  // XW row NN = 128 B of zeros
    if (i < FIN * HD) Wpk0[i] = make_float2(W0[i], rW0[i]);
}

// per-(edge-block, bucket) histogram via LDS; no global atomics
__global__ __launch_bounds__(256) void hist2_kernel(const int* __restrict__ dst,
                                                    int* __restrict__ H) {
    __shared__ int lh[NBUCK2];
    int b = blockIdx.x, tid = threadIdx.x;
    for (int i = tid; i < NBUCK2; i += 256) lh[i] = 0;
    __syncthreads();
    int e0 = b * EPB;
    for (int i = tid; i < EPB; i += 256) atomicAdd(&lh[dst[e0 + i] >> 5], 1);
    __syncthreads();
    for (int i = tid; i < NBUCK2; i += 256) H[b * NBUCK2 + i] = lh[i];
}

// per bucket: exclusive prefix over the 128 blocks; bucket total -> T
__global__ __launch_bounds__(128) void scanA2_kernel(int* __restrict__ H, int* __restrict__ T) {
    __shared__ int l[128];
    int k = blockIdx.x, tid = threadIdx.x;
    int v = H[tid * NBUCK2 + k];
    l[tid] = v;
    __syncthreads();
    for (int off = 1; off < 128; off <<= 1) {
        int t = (tid >= off) ? l[tid - off] : 0;
        __syncthreads();
        l[tid] += t;
        __syncthreads();
    }
    H[tid * NBUCK2 + k] = l[tid] - v;  // exclusive prefix within bucket
    if (tid == 127) T[k] = l[127];
}

// exclusive scan of 1563 bucket totals -> bbase[0..NBUCK2]
__global__ __launch_bounds__(256) void scanB2_kernel(const int* __restrict__ T,
                                                     int* __restrict__ bbase) {
    __shared__ int l[256];
    __shared__ int carry;
    int tid = threadIdx.x;
    if (tid == 0) carry = 0;
    __syncthreads();
    for (int c0 = 0; c0 < NBUCK2; c0 += 256) {
        int v = (c0 + tid < NBUCK2) ? T[c0 + tid] : 0;
        l[tid] = v;
        __syncthreads();
        for (int off = 1; off < 256; off <<= 1) {
            int t = (tid >= off) ? l[tid - off] : 0;
            __syncthreads();
            l[tid] += t;
            __syncthreads();
        }
        if (c0 + tid < NBUCK2) bbase[c0 + tid] = l[tid] - v + carry;
        __syncthreads();
        if (tid == 0) carry += l[255];
        __syncthreads();
    }
    if (tid == 0) bbase[NBUCK2] = carry;  // == NE
}

// H[b][k] += bbase[k]  -> absolute write cursors
__global__ __launch_bounds__(256) void addC_kernel(int* __restrict__ H,
                                                   const int* __restrict__ bbase) {
    int b = blockIdx.x;
    for (int k = threadIdx.x; k < NBUCK2; k += 256) H[b * NBUCK2 + k] += bbase[k];
}

// scatter edges into bucket-grouped packed words: src | (row&31)<<17. LDS cursors only.
__global__ __launch_bounds__(256) void scatter2_kernel(const int* __restrict__ src,
                                                       const int* __restrict__ dst,
                                                       const int* __restrict__ H,
                                                       unsigned* __restrict__ pairs) {
    __shared__ int cur[NBUCK2];
    int b = blockIdx.x, tid = threadIdx.x;
    for (int i = tid; i < NBUCK2; i += 256) cur[i] = H[b * NBUCK2 + i];
    __syncthreads();
    int e0 = b * EPB;
    for (int i = tid; i < EPB; i += 256) {
        int d = dst[e0 + i];
        int s = src[e0 + i];
        int pos = atomicAdd(&cur[d >> 5], 1);
        pairs[pos] = (unsigned)s | ((unsigned)(d & 31) << 17);
    }
}

// ---------------- dense pieces ----------------

// Row-blocked dual GEMM: xw = x @ W1 (bf16); res = relu(x @ W2 + rb) (bf16).
template <int K>
__global__ __launch_bounds__(256) void gemm_dual_kernel(
    const float* __restrict__ x, const float2* __restrict__ Wpk,
    const float* __restrict__ rb, __hip_bfloat16* __restrict__ xw,
    __hip_bfloat16* __restrict__ res, int n) {
    __shared__ float2 sW[K * HD];
    __shared__ float srb[64];
    for (int i = threadIdx.x; i < K * HD; i += 256) sW[i] = Wpk[i];
    if (threadIdx.x < 64) srb[threadIdx.x] = rb[threadIdx.x];
    __syncthreads();
    int wl = threadIdx.x >> 6, lane = threadIdx.x & 63;
    for (int r0 = (blockIdx.x * 4 + wl) * 8; r0 < n; r0 += gridDim.x * 32) {
        float a1[8], a2[8];
#pragma unroll
        for (int r = 0; r < 8; ++r) { a1[r] = 0.f; a2[r] = 0.f; }
#pragma unroll
        for (int c0 = 0; c0 < K; c0 += 64) {
            const int cl = (K - c0 < 64) ? (K - c0) : 64;
            float xv[8];
#pragma unroll
            for (int r = 0; r < 8; ++r) {
                int row = r0 + r;
                xv[r] = (lane < cl && row < n) ? x[(size_t)row * K + c0 + lane] : 0.f;
            }
            for (int j = 0; j < cl; ++j) {
                float2 w = sW[(c0 + j) * HD + lane];
#pragma unroll
                for (int r = 0; r < 8; ++r) {
                    float xb = __uint_as_float(
                        __builtin_amdgcn_readlane(__float_as_uint(xv[r]), j));
                    a1[r] = fmaf(xb, w.x, a1[r]);
                    a2[r] = fmaf(xb, w.y, a2[r]);
                }
            }
        }
#pragma unroll
        for (int r = 0; r < 8; ++r) {
            int row = r0 + r;
            if (row < n) {
                xw[(size_t)row * HD + lane] = __float2bfloat16(a1[r]);
                res[(size_t)row * HD + lane] = __float2bfloat16(fmaxf(a2[r] + srb[lane], 0.f));
            }
        }
    }
}

// BN fold for layer l>=1: writes packed (Wp,rWp) float2 + shiftW + rbp
__global__ void fold_kernel(const float* __restrict__ stats, const float* __restrict__ g,
                            const float* __restrict__ be, const float* __restrict__ W,
                            const float* __restrict__ rW, const float* __restrict__ rb,
                            float2* __restrict__ Wpk, float* __restrict__ shiftW,
                            float* __restrict__ rbp) {
    __shared__ float sc[64], sh[64];
    int t = threadIdx.x;
    if (t < 64) {
        float mean = stats[t] / (float)NN;
        float var = stats[64 + t] / (float)NN - mean * mean;
        float scale = g[t] * rsqrtf(var + BN_EPS);
        sc[t] = scale;
        sh[t] = be[t] - mean * scale;
    }
    __syncthreads();
    for (int i = t; i < 64 * 64; i += 256) {
        int k = i >> 6;
        Wpk[i] = make_float2(sc[k] * W[i], sc[k] * rW[i]);
    }
    if (t < 64) {
        float sw = 0.f, srw = 0.f;
        for (int k = 0; k < 64; ++k) {
            sw = fmaf(sh[k], W[k * 64 + t], sw);
            srw = fmaf(sh[k], rW[k * 64 + t], srw);
        }
        shiftW[t] = sw;
        rbp[t] = rb[t] + srw;
    }
}

__device__ __forceinline__ float bf_lo(unsigned int p) { return __uint_as_float(p << 16); }
__device__ __forceinline__ float bf_hi(unsigned int p) { return __uint_as_float(p & 0xffff0000u); }

// 16-slot branch-free gather batch (pads hit the hot zero row -> L1)
#define GATHER16(BASE)                                             \
    {                                                              \
        unsigned long long d[16];                                  \
        _Pragma("unroll") for (int j = 0; j < 16; ++j) {           \
            int idx = sIdx[rloc][(BASE) + j];                      \
            unsigned off = (unsigned)idx * 16u + (unsigned)c8;     \
            d[j] = XWu[off];                                       \
        }                                                          \
        _Pragma("unroll") for (int j = 0; j < 16; ++j) {           \
            unsigned lo = (unsigned)d[j], hi = (unsigned)(d[j] >> 32); \
            a0 += bf_lo(lo); a1 += bf_hi(lo);                      \
            a2 += bf_lo(hi); a3 += bf_hi(hi);                      \
        }                                                          \
    }

// fused aggregation v5: stages its own 32-row bucket from packed pairs (LDS ranking);
// 16 lanes/row, 4 rows in flight, fixed-16 branch-free phases; LDS overflow for deg>32.
__global__ __launch_bounds__(256, 4) void fused_agg_kernel(
    const __hip_bfloat16* __restrict__ xw, const __hip_bfloat16* __restrict__ res,
    const float* __restrict__ b, const float* __restrict__ shiftW,
    const int* __restrict__ bbase, const unsigned* __restrict__ pairs,
    float* __restrict__ hout, float* __restrict__ stats, int n) {
    __shared__ int sIdx[CHUNK][ELLW + 1];  // +1 pad
    __shared__ int sLen[CHUNK];            // rank counters == degrees after staging
    __shared__ unsigned oflow[OCAP];
    __shared__ int ocnt;
    __shared__ int sBB[2];
    __shared__ float sbb[128];             // b | shiftW
    __shared__ float lsr[4][16][8];

    int tid = threadIdx.x;
    int r0 = blockIdx.x * CHUNK;

    for (int i = tid; i < CHUNK * (ELLW + 1); i += 256) ((int*)sIdx)[i] = NN;
    if (tid < CHUNK) sLen[tid] = 0;
    if (tid == 0) ocnt = 0;
    if (tid < 2) sBB[tid] = bbase[blockIdx.x + tid];
    if (tid >= 128 && tid < 256) {
        int j = tid - 128;
        sbb[j] = (j < 64) ? b[j] : (shiftW ? shiftW[j - 64] : 0.f);
    }
    __syncthreads();
    int beg = sBB[0], end = sBB[1];
    for (int i = beg + tid; i < end; i += 256) {
        unsigned v = pairs[i];
        int rloc = (int)(v >> 17);
        int rk = atomicAdd(&sLen[rloc], 1);
        if (rk < ELLW) {
            sIdx[rloc][rk] = (int)(v & 0x1FFFFu);
        } else {
            int o = atomicAdd(&ocnt, 1);
            if (o < OCAP) oflow[o] = v;
        }
    }
    __syncthreads();
    int noflow = (ocnt < OCAP) ? ocnt : OCAP;

    const unsigned long long* XWu = (const unsigned long long*)xw;
    const unsigned long long* REu = (const unsigned long long*)res;
    int wl = tid >> 6, lane = tid & 63;
    int q = lane >> 4, c8 = lane & 15;
    float sb0 = sbb[4 * c8], sb1 = sbb[4 * c8 + 1], sb2 = sbb[4 * c8 + 2], sb3 = sbb[4 * c8 + 3];
    float sw0 = sbb[64 + 4 * c8], sw1 = sbb[64 + 4 * c8 + 1];
    float sw2 = sbb[64 + 4 * c8 + 2], sw3 = sbb[64 + 4 * c8 + 3];
    float s0 = 0.f, s1 = 0.f, s2 = 0.f, s3 = 0.f;
    float q0 = 0.f, q1 = 0.f, q2 = 0.f, q3 = 0.f;

#pragma unroll
    for (int p = 0; p < 2; ++p) {
        int rbase = wl * 8 + p * 4;
        int rloc = rbase + q;
        int grow = r0 + rloc;
        int growc = (grow < n) ? grow : (n - 1);
        int l0 = sLen[rbase], l1 = sLen[rbase + 1], l2 = sLen[rbase + 2], l3 = sLen[rbase + 3];
        int m01 = (l0 > l1) ? l0 : l1, m23 = (l2 > l3) ? l2 : l3;
        int kmax = (m01 > m23) ? m01 : m23;  // wave-uniform
        int mylen = sLen[rloc];
        unsigned long long rqw = REu[(unsigned)growc * 16u + (unsigned)c8];  // residual early
        float a0 = 0.f, a1 = 0.f, a2 = 0.f, a3 = 0.f;
        GATHER16(0)
        if (kmax > 16) GATHER16(16)
        if (kmax > ELLW) {  // rare: scan LDS overflow list (entries are ranks >= ELLW)
            for (int o = 0; o < noflow; ++o) {
                unsigned v = oflow[o];
                if ((int)(v >> 17) == rloc) {
                    unsigned off = (v & 0x1FFFFu) * 16u + (unsigned)c8;
                    unsigned long long u = XWu[off];
                    unsigned lo = (unsigned)u, hi = (unsigned)(u >> 32);
                    a0 += bf_lo(lo); a1 += bf_hi(lo);
                    a2 += bf_lo(hi); a3 += bf_hi(hi);
                }
            }
        }
        unsigned rlo = (unsigned)rqw, rhi = (unsigned)(rqw >> 32);
        float dg = (float)mylen;
        float h0 = fmaxf(a0 + fmaf(dg, sw0, sb0), 0.f) + bf_lo(rlo);
        float h1 = fmaxf(a1 + fmaf(dg, sw1, sb1), 0.f) + bf_hi(rlo);
        float h2 = fmaxf(a2 + fmaf(dg, sw2, sb2), 0.f) + bf_lo(rhi);
        float h3 = fmaxf(a3 + fmaf(dg, sw3, sb3), 0.f) + bf_hi(rhi);
        if (grow < n) {
            *(float4*)&hout[(unsigned)grow * 64u + 4u * c8] = make_float4(h0, h1, h2, h3);
            s0 += h0; s1 += h1; s2 += h2; s3 += h3;
            q0 += h0 * h0; q1 += h1 * h1; q2 += h2 * h2; q3 += h3 * h3;
        }
    }

    // reduce across the 4 quarters of the wave (same c8 -> same columns)
    s0 += __shfl_xor(s0, 16, 64); s0 += __shfl_xor(s0, 32, 64);
    s1 += __shfl_xor(s1, 16, 64); s1 += __shfl_xor(s1, 32, 64);
    s2 += __shfl_xor(s2, 16, 64); s2 += __shfl_xor(s2, 32, 64);
    s3 += __shfl_xor(s3, 16, 64); s3 += __shfl_xor(s3, 32, 64);
    q0 += __shfl_xor(q0, 16, 64); q0 += __shfl_xor(q0, 32, 64);
    q1 += __shfl_xor(q1, 16, 64); q1 += __shfl_xor(q1, 32, 64);
    q2 += __shfl_xor(q2, 16, 64); q2 += __shfl_xor(q2, 32, 64);
    q3 += __shfl_xor(q3, 16, 64); q3 += __shfl_xor(q3, 32, 64);
    if (q == 0) {
        lsr[wl][c8][0] = s0; lsr[wl][c8][1] = s1; lsr[wl][c8][2] = s2; lsr[wl][c8][3] = s3;
        lsr[wl][c8][4] = q0; lsr[wl][c8][5] = q1; lsr[wl][c8][6] = q2; lsr[wl][c8][7] = q3;
    }
    __syncthreads();
    if (tid < 64) {
        int c8i = tid >> 2, comp = tid & 3;
        float ssum = lsr[0][c8i][comp] + lsr[1][c8i][comp] + lsr[2][c8i][comp] + lsr[3][c8i][comp];
        float qsum = lsr[0][c8i][4 + comp] + lsr[1][c8i][4 + comp] + lsr[2][c8i][4 + comp] +
                     lsr[3][c8i][4 + comp];
        atomicAdd(&stats[tid], ssum);
        atomicAdd(&stats[64 + tid], qsum);
    }
}

// ---------------- readout ----------------

__global__ void readout_init_kernel(float* __restrict__ hsum, unsigned int* __restrict__ hmax,
                                    const float* __restrict__ stats, const float* __restrict__ g,
                                    const float* __restrict__ be, float* __restrict__ ss) {
    int idx = blockIdx.x * 256 + threadIdx.x;
    if (idx < NB * HD) {
        hsum[idx] = 0.f;
        hmax[idx] = 0x007FFFFFu;  // encoded(-inf)
    }
    if (blockIdx.x == 0 && threadIdx.x < 64) {
        int c = threadIdx.x;
        float mean = stats[c] / (float)NN;
        float var = stats[64 + c] / (float)NN - mean * mean;
        float scale = g[c] * rsqrtf(var + BN_EPS);
        ss[c] = scale;
        ss[64 + c] = be[c] - mean * scale;
    }
}

#define RNODES 16

__device__ __forceinline__ void ro_flush(float* hsum, unsigned int* hmax, int g, int c,
                                         float accS, float accM) {
    atomicAdd(&hsum[g * HD + c], accS);
    unsigned int bits = __float_as_uint(accM);
    unsigned int enc = (bits & 0x80000000u) ? ~bits : (bits | 0x80000000u);
    atomicMax(&hmax[g * HD + c], enc);
}

__global__ __launch_bounds__(256) void readout_kernel(
    const float* __restrict__ h, const int* __restrict__ gid, const float* __restrict__ ss,
    const float* __restrict__ awW, const float* __restrict__ awb, float* __restrict__ hsum,
    unsigned int* __restrict__ hmax, int n) {
    int wid = blockIdx.x * 4 + (threadIdx.x >> 6);
    int c = threadIdx.x & 63;
    int r0 = wid * RNODES;
    if (r0 >= n) return;
    int r1 = r0 + RNODES;
    if (r1 > n) r1 = n;
    float aw = awW[c], ab = awb[0];
    float sA = ss[c], sB = ss[64 + c];
    int cur = gid[r0];
    float accS = 0.f, accM = -__builtin_inff();
    for (int r = r0; r < r1; ++r) {
        int g = gid[r];
        if (g != cur) {
            ro_flush(hsum, hmax, cur, c, accS, accM);
            accS = 0.f;
            accM = -__builtin_inff();
            cur = g;
        }
        float v = fmaf(h[(size_t)r * HD + c], sA, sB);
        float p = v * aw;
        for (int off = 32; off; off >>= 1) p += __shfl_xor(p, off, 64);
        float w = 1.f / (1.f + expf(-(p + ab)));
        accS = fmaf(v, w, accS);
        accM = fmaxf(accM, v);
    }
    ro_flush(hsum, hmax, cur, c, accS, accM);
}

__global__ void final_kernel(const float* __restrict__ hsum, const unsigned int* __restrict__ hmax,
                             const float* __restrict__ outW, const float* __restrict__ outb,
                             float* __restrict__ out) {
    __shared__ float sW[128 * 64];
    for (int i = threadIdx.x; i < 128 * 64; i += 256) sW[i] = outW[i];
    __syncthreads();
    int idx = blockIdx.x * 256 + threadIdx.x;
    if (idx >= NB * HD) return;
    int bi = idx >> 6, o = idx & 63;
    float acc = outb[o];
#pragma unroll 4
    for (int k = 0; k < 64; ++k) acc = fmaf(hsum[bi * 64 + k], sW[k * 64 + o], acc);
#pragma unroll 4
    for (int k = 0; k < 64; ++k) {
        unsigned int e = hmax[bi * 64 + k];
        float m;
        if (e == 0x007FFFFFu) {
            m = 0.f;  // empty graph
        } else {
            m = (e & 0x80000000u) ? __uint_as_float(e ^ 0x80000000u) : __uint_as_float(~e);
        }
        acc = fmaf(m, sW[(64 + k) * 64 + o], acc);
    }
    out[idx] = acc;
}

// ---------------- launch ----------------

extern "C" void kernel_launch(void* const* d_in, const int* in_sizes, int n_in,
                              void* d_out, int out_size, void* d_ws, size_t ws_size,
                              hipStream_t stream) {
    const float* feats = (const float*)d_in[0];
    const int* src = (const int*)d_in[1];
    const int* dst = (const int*)d_in[2];
    const int* gid = (const int*)d_in[3];
    const float* W[3];
    const float* b[3];
    const float* rW[3];
    const float* rb[3];
    const float* g[3];
    const float* be[3];
    for (int l = 0; l < 3; ++l) {
        W[l] = (const float*)d_in[4 + 6 * l + 0];
        b[l] = (const float*)d_in[4 + 6 * l + 1];
        rW[l] = (const float*)d_in[4 + 6 * l + 2];
        rb[l] = (const float*)d_in[4 + 6 * l + 3];
        g[l] = (const float*)d_in[4 + 6 * l + 4];
        be[l] = (const float*)d_in[4 + 6 * l + 5];
    }
    const float* awW = (const float*)d_in[22];
    const float* awb = (const float*)d_in[23];
    const float* outW = (const float*)d_in[24];
    const float* outb = (const float*)d_in[25];
    float* out = (float*)d_out;

    // workspace layout
    __hip_bfloat16* XW = (__hip_bfloat16*)d_ws;                 // (NN+1)*64 bf16 (row NN zeros)
    __hip_bfloat16* RES = XW + (size_t)(NN + 1) * HD;           // NN*64 bf16
    float* P1 = (float*)(RES + (size_t)NN * HD);                // N*64 f32 (h, in place)
    float* stats = P1 + (size_t)NN * HD;                        // 3*128
    float* ss2 = stats + 384;                                   // 128
    float2* WPK = (float2*)(ss2 + 128);                         // FIN*HD float2
    float* shW = (float*)(WPK + FIN * HD);                      // 64
    float* rbp = shW + 64;                                      // 64
    float* hsum = rbp + 64;                                     // B*64
    unsigned int* hmax = (unsigned int*)(hsum + (size_t)NB * HD);  // B*64
    unsigned* pairs = (unsigned*)(hmax + (size_t)NB * HD);      // NE packed words
    int* H = (int*)(pairs + (size_t)NE);                        // EB2*NBUCK2
    int* T = H + (size_t)EB2 * NBUCK2;                          // NBUCK2
    int* bbase = T + NBUCK2;                                    // NBUCK2+1

    float* stats0 = stats;
    float* stats1 = stats + 128;
    float* stats2 = stats + 256;

    const int GEMMBLK = 1280;
    const int ROBLK = (NN + RNODES * 4 - 1) / (RNODES * 4);

    // ---- build: contention-free bucket counting sort + layer-0 weight pack ----
    init_kernel<<<(FIN * HD + 255) / 256, 256, 0, stream>>>(
        stats, (unsigned long long*)(XW + (size_t)NN * HD), W[0], rW[0], WPK);
    hist2_kernel<<<EB2, 256, 0, stream>>>(dst, H);
    scanA2_kernel<<<NBUCK2, 128, 0, stream>>>(H, T);
    scanB2_kernel<<<1, 256, 0, stream>>>(T, bbase);
    addC_kernel<<<EB2, 256, 0, stream>>>(H, bbase);
    scatter2_kernel<<<EB2, 256, 0, stream>>>(src, dst, H, pairs);

    // ---- layer 0 ----
    gemm_dual_kernel<FIN><<<GEMMBLK, 256, 0, stream>>>(feats, WPK, rb[0], XW, RES, NN);
    fused_agg_kernel<<<NBLK, 256, 0, stream>>>(XW, RES, b[0], (const float*)nullptr, bbase,
                                               pairs, P1, stats0, NN);

    // ---- layer 1 (fold BN0) ----
    fold_kernel<<<1, 256, 0, stream>>>(stats0, g[0], be[0], W[1], rW[1], rb[1], WPK, shW, rbp);
    gemm_dual_kernel<HD><<<GEMMBLK, 256, 0, stream>>>(P1, WPK, rbp, XW, RES, NN);
    fused_agg_kernel<<<NBLK, 256, 0, stream>>>(XW, RES, b[1], shW, bbase, pairs, P1, stats1, NN);

    // ---- layer 2 (fold BN1) ----
    fold_kernel<<<1, 256, 0, stream>>>(stats1, g[1], be[1], W[2], rW[2], rb[2], WPK, shW, rbp);
    gemm_dual_kernel<HD><<<GEMMBLK, 256, 0, stream>>>(P1, WPK, rbp, XW, RES, NN);
    fused_agg_kernel<<<NBLK, 256, 0, stream>>>(XW, RES, b[2], shW, bbase, pairs, P1, stats2, NN);

    // ---- readout (BN2 on the fly) ----
    readout_init_kernel<<<(NB * HD + 255) / 256, 256, 0, stream>>>(hsum, hmax, stats2, g[2], be[2], ss2);
    readout_kernel<<<ROBLK, 256, 0, stream>>>(P1, gid, ss2, awW, awb, hsum, hmax, NN);
    final_kernel<<<(NB * HD + 255) / 256, 256, 0, stream>>>(hsum, hmax, outW, outb, out);
}